// Round 3
// baseline (697.349 us; speedup 1.0000x reference)
//
#include <hip/hip_runtime.h>
#include <cstdint>
#include <cstddef>

// ---------------------------------------------------------------------------
// StokenAttention forward, MI355X. B=8, C=256, H=W=128, stoken 8x8 -> 16x16
// grid, n=256 stokens/batch, 64 px/stoken, NH=8 heads, HD=KD=32.
// ALL inputs fp32, output fp32 (confirmed by round-1/2 bisect: bf16 reads of
// x produced NaN; bf16 writes to out produced position-scrambled readback).
// ---------------------------------------------------------------------------

#define AFF_SCALE 0.0625f               // 256^-0.5
#define ATTN_SCALE 0.17677669529663687f // 32^-0.5

// ---------------------------------------------------------------------------
// K1: stoken avg-pool. grid = B*C*16 (blk = (b*256+c)*16 + i), block = 128.
// Writes into zero-padded stok_pad[b][c][18][18] interior.
// ---------------------------------------------------------------------------
__global__ __launch_bounds__(128) void stoken_kernel(
    const float* __restrict__ x, float* __restrict__ stok_pad)
{
    int blk = blockIdx.x;
    int i  = blk & 15;
    int bc = blk >> 4;                 // b*256 + c
    int t  = threadIdx.x;              // col 0..127
    const float* xr = x + ((size_t)bc * 128 + i * 8) * 128 + t;
    float s = 0.f;
#pragma unroll
    for (int r = 0; r < 8; ++r) s += xr[r * 128];
    s += __shfl_down(s, 4, 64);
    s += __shfl_down(s, 2, 64);
    s += __shfl_down(s, 1, 64);
    if ((t & 7) == 0) {
        int j = t >> 3;  // 0..15
        stok_pad[((size_t)bc * 18 + (i + 1)) * 18 + (j + 1)] = s * (1.f / 64.f);
    }
}

// ---------------------------------------------------------------------------
// K2: fused affinity + asum + aggregation-scatter. grid = B*256, block = 256.
//   phase 1: logits[p][k] = sum_c pix[p][c]*sf9[c][k]  (lane=p, wave=c-quarter)
//   phase 1.5: softmax over 9 (wave 0), write aff + asum
//   phase 2: agg[c][k] = sum_p pix[c][p]*aff[p][k] (thread=c), atomic fold
// pixs stride 65: conflict-free for both lane=p (stride 1) and lane=c
// (stride 65 ~ stride 1 mod 32) access phases.
// ---------------------------------------------------------------------------
__global__ __launch_bounds__(256) void aff_agg_kernel(
    const float* __restrict__ x, const float* __restrict__ stok_pad,
    float* __restrict__ aff_g, float* __restrict__ asum_g,
    float* __restrict__ sf_raw)
{
    __shared__ float pixs[256 * 65];          // [c][65 pad] fp32 (66.6 KB)
    __shared__ float part[4 * 64 * 9];        // wave partials
    __shared__ float affs[9 * 64];            // aff [k][p]

    int bn = blockIdx.x;
    int n = bn & 255, b = bn >> 8;
    int i = n >> 4, j = n & 15;
    int t = threadIdx.x;

    // ---- stage pixel tile: 256 c x 64 p (8x8 px), 2x float4 per row-of-8 ----
    {
        int c0 = t >> 3, pi = t & 7;
#pragma unroll
        for (int it = 0; it < 8; ++it) {
            int c = c0 + 32 * it;
            const float* xp = x + (((size_t)b * 256 + c) * 128 + i * 8 + pi) * 128 + j * 8;
            const float4 f0 = *(const float4*)&xp[0];
            const float4 f1 = *(const float4*)&xp[4];
            float* d = &pixs[c * 65 + pi * 8];
            d[0] = f0.x; d[1] = f0.y; d[2] = f0.z; d[3] = f0.w;
            d[4] = f1.x; d[5] = f1.y; d[6] = f1.z; d[7] = f1.w;
        }
    }
    __syncthreads();

    // ---- phase 1: partial logits (wave s handles channels s*64..+63) ----
    int s = t >> 6, p = t & 63;
    float acc[9] = {0.f,0.f,0.f,0.f,0.f,0.f,0.f,0.f,0.f};
    {
        const float* sp = stok_pad + ((size_t)b * 256 + s * 64) * 324 + i * 18 + j;
        for (int cc = 0; cc < 64; ++cc) {
            float px = pixs[(s * 64 + cc) * 65 + p];
            const float* q = sp + cc * 324;  // wave-uniform -> broadcast loads
            acc[0] += px * q[0];  acc[1] += px * q[1];  acc[2] += px * q[2];
            acc[3] += px * q[18]; acc[4] += px * q[19]; acc[5] += px * q[20];
            acc[6] += px * q[36]; acc[7] += px * q[37]; acc[8] += px * q[38];
        }
    }
#pragma unroll
    for (int k = 0; k < 9; ++k) part[(s * 64 + p) * 9 + k] = acc[k];
    __syncthreads();

    // ---- phase 1.5: softmax over 9 (wave 0), aff + asum writes ----
    if (t < 64) {
        float a[9];
        float mx = -1e30f;
#pragma unroll
        for (int k = 0; k < 9; ++k) {
            float v = (part[(0 * 64 + t) * 9 + k] + part[(1 * 64 + t) * 9 + k] +
                       part[(2 * 64 + t) * 9 + k] + part[(3 * 64 + t) * 9 + k]) * AFF_SCALE;
            a[k] = v;
            mx = fmaxf(mx, v);
        }
        float ssum = 0.f;
#pragma unroll
        for (int k = 0; k < 9; ++k) { a[k] = __expf(a[k] - mx); ssum += a[k]; }
        float inv = 1.f / ssum;
#pragma unroll
        for (int k = 0; k < 9; ++k) {
            a[k] *= inv;
            affs[k * 64 + t] = a[k];
            aff_g[(size_t)bn * 576 + k * 64 + t] = a[k];
        }
#pragma unroll
        for (int k = 0; k < 9; ++k) {
            float r = a[k];
            r += __shfl_down(r, 32, 64); r += __shfl_down(r, 16, 64);
            r += __shfl_down(r, 8, 64);  r += __shfl_down(r, 4, 64);
            r += __shfl_down(r, 2, 64);  r += __shfl_down(r, 1, 64);
            if (t == 0) asum_g[(size_t)bn * 9 + k] = r;
        }
    }
    __syncthreads();

    // ---- phase 2: aggregation + atomic fold-scatter (thread = channel) ----
    {
        int c = t;
        float a9[9] = {0.f,0.f,0.f,0.f,0.f,0.f,0.f,0.f,0.f};
        for (int p4 = 0; p4 < 16; ++p4) {
            float px0 = pixs[c * 65 + p4 * 4 + 0];
            float px1 = pixs[c * 65 + p4 * 4 + 1];
            float px2 = pixs[c * 65 + p4 * 4 + 2];
            float px3 = pixs[c * 65 + p4 * 4 + 3];
#pragma unroll
            for (int k = 0; k < 9; ++k) {
                const float4 av = *(const float4*)&affs[k * 64 + p4 * 4]; // uniform
                a9[k] += px0 * av.x + px1 * av.y + px2 * av.z + px3 * av.w;
            }
        }
#pragma unroll
        for (int k = 0; k < 9; ++k) {
            int dy = k / 3, dx = k % 3;
            int y = i + dy - 1, xx = j + dx - 1;
            if ((unsigned)y < 16u && (unsigned)xx < 16u)
                atomicAdd(&sf_raw[(((size_t)b * 256 + c) * 16 + y) * 16 + xx], a9[k]);
        }
    }
}

// ---------------------------------------------------------------------------
// K3: sf = sf_raw / (fold(asum) + 1e-12). In-place safe (elementwise).
// ---------------------------------------------------------------------------
__global__ __launch_bounds__(256) void sfdiv_kernel(
    const float* __restrict__ sf_raw, const float* __restrict__ asum_g,
    float* __restrict__ sf)
{
    int bc = blockIdx.x;
    int b = bc >> 8;
    int t = threadIdx.x;
    int y = t >> 4, x = t & 15;
    float af = 0.f;
#pragma unroll
    for (int dy = 0; dy < 3; ++dy)
#pragma unroll
        for (int dx = 0; dx < 3; ++dx) {
            int ii = y + 1 - dy, jj = x + 1 - dx;
            if ((unsigned)ii < 16u && (unsigned)jj < 16u)
                af += asum_g[((size_t)b * 256 + ii * 16 + jj) * 9 + dy * 3 + dx];
        }
    float v = sf_raw[(size_t)bc * 256 + t];
    sf[(size_t)bc * 256 + t] = v / (af + 1e-12f);
}

// ---------------------------------------------------------------------------
// K4/K7: GEMM out[b][o][n] = sum_c A[o][c] * Bm[b][c][n]. A fp32 (row-major,
// lda=256), Bm fp32 [b][256][256]. mode 0: fp32 out [b][M][256]. mode 1:
// write into padded [b][18][18][256] (+1 spatial offset).
// grid = (8, M/64, 4), block = 256, 64x64 tile, 4x4 micro.
// ---------------------------------------------------------------------------
__global__ __launch_bounds__(256) void gemm_w(
    const float* __restrict__ A, const float* __restrict__ Bm,
    float* __restrict__ Cout, int M, int mode)
{
    __shared__ float As[32 * 68];
    __shared__ float Bs[32 * 64];
    int b = blockIdx.x, o0 = blockIdx.y * 64, n0 = blockIdx.z * 64;
    int t = threadIdx.x;
    int tr = t >> 4, tc = t & 15;
    const float* Bb = Bm + (size_t)b * 256 * 256;
    float acc[4][4];
#pragma unroll
    for (int ii = 0; ii < 4; ++ii)
#pragma unroll
        for (int jj = 0; jj < 4; ++jj) acc[ii][jj] = 0.f;

    for (int k0 = 0; k0 < 256; k0 += 32) {
        {
            int ol = t >> 2, kq = (t & 3) * 8;
            const float* Ap = A + (size_t)(o0 + ol) * 256 + k0 + kq;
            const float4 f0 = *(const float4*)&Ap[0];
            const float4 f1 = *(const float4*)&Ap[4];
            As[(kq + 0) * 68 + ol] = f0.x; As[(kq + 1) * 68 + ol] = f0.y;
            As[(kq + 2) * 68 + ol] = f0.z; As[(kq + 3) * 68 + ol] = f0.w;
            As[(kq + 4) * 68 + ol] = f1.x; As[(kq + 5) * 68 + ol] = f1.y;
            As[(kq + 6) * 68 + ol] = f1.z; As[(kq + 7) * 68 + ol] = f1.w;
        }
#pragma unroll
        for (int i2 = 0; i2 < 8; ++i2) {
            int e = t + i2 * 256;
            int kl = e >> 6, nl = e & 63;
            Bs[kl * 64 + nl] = Bb[(size_t)(k0 + kl) * 256 + n0 + nl];
        }
        __syncthreads();
#pragma unroll
        for (int kk = 0; kk < 32; ++kk) {
            const float4 av = *(const float4*)&As[kk * 68 + tr * 4];
            const float4 bv = *(const float4*)&Bs[kk * 64 + tc * 4];
            acc[0][0] += av.x * bv.x; acc[0][1] += av.x * bv.y; acc[0][2] += av.x * bv.z; acc[0][3] += av.x * bv.w;
            acc[1][0] += av.y * bv.x; acc[1][1] += av.y * bv.y; acc[1][2] += av.y * bv.z; acc[1][3] += av.y * bv.w;
            acc[2][0] += av.z * bv.x; acc[2][1] += av.z * bv.y; acc[2][2] += av.z * bv.z; acc[2][3] += av.z * bv.w;
            acc[3][0] += av.w * bv.x; acc[3][1] += av.w * bv.y; acc[3][2] += av.w * bv.z; acc[3][3] += av.w * bv.w;
        }
        __syncthreads();
    }

    if (mode == 0) {
#pragma unroll
        for (int ii = 0; ii < 4; ++ii) {
            int o = o0 + tr * 4 + ii;
            float4 st = make_float4(acc[ii][0], acc[ii][1], acc[ii][2], acc[ii][3]);
            *(float4*)&Cout[((size_t)b * M + o) * 256 + n0 + tc * 4] = st;
        }
    } else {
#pragma unroll
        for (int jj = 0; jj < 4; ++jj) {
            int n = n0 + tc * 4 + jj;
            int y = n >> 4, x = n & 15;
            float4 st = make_float4(acc[0][jj], acc[1][jj], acc[2][jj], acc[3][jj]);
            *(float4*)&Cout[(((size_t)b * 18 + 1 + y) * 18 + 1 + x) * 256 + o0 + tr * 4] = st;
        }
    }
}

// ---------------------------------------------------------------------------
// K5: attention. grid = (8 b, 8 h, 4 n-tiles), block = 256.
// K then V staged sequentially in the same 32KB LDS buffer; logits stay in
// registers across the swap. Quarter-softmax combined through LDS at the end.
// ---------------------------------------------------------------------------
__global__ __launch_bounds__(256) void attn_kernel(
    const float* __restrict__ qkv, float* __restrict__ o_attn)
{
    __shared__ float smem[9216]; // 36,864 B
    int b = blockIdx.x, h = blockIdx.y, nt = blockIdx.z;
    int t = threadIdx.x, nl = t & 63, mq = t >> 6;
    int n = nt * 64 + nl;

    // stage K -> smem[m][32]
    {
        int dd = t >> 3, mb = (t & 7) * 32;
        const float* krow = qkv + ((size_t)b * 768 + h * 96 + 32 + dd) * 256;
#pragma unroll
        for (int e4 = 0; e4 < 8; ++e4) {
            int m = mb + e4 * 4;
            const float4 kw = *(const float4*)&krow[m];
            smem[(m + 0) * 32 + dd] = kw.x; smem[(m + 1) * 32 + dd] = kw.y;
            smem[(m + 2) * 32 + dd] = kw.z; smem[(m + 3) * 32 + dd] = kw.w;
        }
    }
    float q[32];
    {
        const float* qbase = qkv + ((size_t)b * 768 + h * 96) * 256 + n;
#pragma unroll
        for (int d = 0; d < 32; ++d) q[d] = qbase[(size_t)d * 256];
    }
    __syncthreads();

    // pass 1: logits for this quarter's 64 m's
    float l[64];
#pragma unroll
    for (int e = 0; e < 64; ++e) {
        const float* kp = &smem[(mq * 64 + e) * 32];
        float s = 0.f;
#pragma unroll
        for (int d4 = 0; d4 < 8; ++d4) {
            const float4 kv4 = *(const float4*)&kp[d4 * 4];
            s += q[d4 * 4 + 0] * kv4.x + q[d4 * 4 + 1] * kv4.y +
                 q[d4 * 4 + 2] * kv4.z + q[d4 * 4 + 3] * kv4.w;
        }
        l[e] = s * ATTN_SCALE;
    }
    float mx = -1e30f;
#pragma unroll
    for (int e = 0; e < 64; ++e) mx = fmaxf(mx, l[e]);
    float sm = 0.f;
#pragma unroll
    for (int e = 0; e < 64; ++e) { l[e] = __expf(l[e] - mx); sm += l[e]; }
    __syncthreads();  // everyone done reading K

    // stage V -> same smem[m][32]
    {
        int dd = t >> 3, mb = (t & 7) * 32;
        const float* vrow = qkv + ((size_t)b * 768 + h * 96 + 64 + dd) * 256;
#pragma unroll
        for (int e4 = 0; e4 < 8; ++e4) {
            int m = mb + e4 * 4;
            const float4 vw = *(const float4*)&vrow[m];
            smem[(m + 0) * 32 + dd] = vw.x; smem[(m + 1) * 32 + dd] = vw.y;
            smem[(m + 2) * 32 + dd] = vw.z; smem[(m + 3) * 32 + dd] = vw.w;
        }
    }
    __syncthreads();

    // pass 2: o partial = sum_m p[m] * v[m][:]
    float oa[32];
#pragma unroll
    for (int d = 0; d < 32; ++d) oa[d] = 0.f;
#pragma unroll
    for (int e = 0; e < 64; ++e) {
        float pm = l[e];
        const float* vp = &smem[(mq * 64 + e) * 32];
#pragma unroll
        for (int d4 = 0; d4 < 8; ++d4) {
            const float4 vv = *(const float4*)&vp[d4 * 4];
            oa[d4 * 4 + 0] += pm * vv.x; oa[d4 * 4 + 1] += pm * vv.y;
            oa[d4 * 4 + 2] += pm * vv.z; oa[d4 * 4 + 3] += pm * vv.w;
        }
    }
    __syncthreads();  // everyone done reading V -> reuse smem

    float* op   = smem;          // [mq*64+nl][33] -> 8448 floats
    float* mxsm = smem + 8448;   // [idx][2]       -> 512 floats
    {
        int idx = mq * 64 + nl;
#pragma unroll
        for (int d = 0; d < 32; ++d) op[idx * 33 + d] = oa[d];
        mxsm[idx * 2 + 0] = mx;
        mxsm[idx * 2 + 1] = sm;
    }
    __syncthreads();

    if (t < 64) {
        float M2 = -1e30f;
#pragma unroll
        for (int q4 = 0; q4 < 4; ++q4) M2 = fmaxf(M2, mxsm[(q4 * 64 + t) * 2]);
        float w[4], S = 0.f;
#pragma unroll
        for (int q4 = 0; q4 < 4; ++q4) {
            w[q4] = __expf(mxsm[(q4 * 64 + t) * 2] - M2);
            S += mxsm[(q4 * 64 + t) * 2 + 1] * w[q4];
        }
        float inv = 1.f / S;
#pragma unroll
        for (int d = 0; d < 32; ++d) {
            float o = 0.f;
#pragma unroll
            for (int q4 = 0; q4 < 4; ++q4) o += op[(q4 * 64 + t) * 33 + d] * w[q4];
            o_attn[((size_t)b * 256 + h * 32 + d) * 256 + nt * 64 + t] = o * inv;
        }
    }
}

// ---------------------------------------------------------------------------
// K6: o += depthwise 3x3 PE conv of V (in-place on o_attn). grid B*C, blk 256.
// ---------------------------------------------------------------------------
__global__ __launch_bounds__(256) void peadd_kernel(
    const float* __restrict__ qkv, const float* __restrict__ w_pe,
    float* __restrict__ o_attn)
{
    int bc = blockIdx.x;
    int b = bc >> 8, c = bc & 255;
    int t = threadIdx.x;
    int y = t >> 4, x = t & 15;
    int h = c >> 5, d = c & 31;
    const float* v = qkv + ((size_t)b * 768 + h * 96 + 64 + d) * 256;
    float acc = o_attn[(size_t)bc * 256 + t];
#pragma unroll
    for (int ky = 0; ky < 3; ++ky)
#pragma unroll
        for (int kx = 0; kx < 3; ++kx) {
            int yy = y + ky - 1, xx = x + kx - 1;
            if ((unsigned)yy < 16u && (unsigned)xx < 16u)
                acc += w_pe[c * 9 + ky * 3 + kx] * v[yy * 16 + xx];
        }
    o_attn[(size_t)bc * 256 + t] = acc;
}

// ---------------------------------------------------------------------------
// K8: scatter back to pixels with the reference's (p,c) scramble:
// out[b,c2,i*8+pi,j*8+pj] = sum_k sfa[b, (c2&3)*64+pi*8+pj, k-neighborhood]
//                                  * aff[b, n, c2>>2, k]
// ---------------------------------------------------------------------------
__global__ __launch_bounds__(256) void scatter_kernel(
    const float* __restrict__ sfa_pad, const float* __restrict__ aff_g,
    float* __restrict__ out)
{
    __shared__ float s9[256 * 13]; // [cc][9 of (dy,dx)]
    __shared__ float af[64 * 12];  // [p][9]

    int bn = blockIdx.x;
    int b = bn >> 8, n = bn & 255;
    int i = n >> 4, j = n & 15;
    int t = threadIdx.x;

#pragma unroll
    for (int k = 0; k < 9; ++k)
        s9[t * 13 + k] = sfa_pad[(((size_t)b * 18 + i + k / 3) * 18 + (j + k % 3)) * 256 + t];
#pragma unroll
    for (int r = 0; r < 3; ++r) {
        int e = t + r * 256;
        if (e < 576) af[(e & 63) * 12 + (e >> 6)] = aff_g[(size_t)bn * 576 + e];
    }
    __syncthreads();

    int lane = t & 63, s = t >> 6;
    int pi2 = lane >> 3, pj2 = lane & 7;

    float s9r[36];
#pragma unroll
    for (int q4 = 0; q4 < 4; ++q4)
#pragma unroll
        for (int k = 0; k < 9; ++k)
            s9r[q4 * 9 + k] = s9[(q4 * 64 + lane) * 13 + k];

    size_t obase = (size_t)b * 256 * 16384 + (size_t)(i * 8 + pi2) * 128 + j * 8 + pj2;
#pragma unroll
    for (int pg = 0; pg < 16; ++pg) {
        int p = s * 16 + pg;
        const float4 a0 = *(const float4*)&af[p * 12];
        const float4 a1 = *(const float4*)&af[p * 12 + 4];
        const float  a8 = af[p * 12 + 8];
#pragma unroll
        for (int q4 = 0; q4 < 4; ++q4) {
            int c2 = s * 64 + pg * 4 + q4;
            const float* sr = &s9r[q4 * 9];
            float v = sr[0] * a0.x + sr[1] * a0.y + sr[2] * a0.z + sr[3] * a0.w +
                      sr[4] * a1.x + sr[5] * a1.y + sr[6] * a1.z + sr[7] * a1.w +
                      sr[8] * a8;
            out[obase + (size_t)c2 * 16384] = v;
        }
    }
}

// ---------------------------------------------------------------------------
// launch. Workspace (floats), lifetime-aliased, 15.8 MB total:
//   o_aff  [0,          1179648)   aff        (live to end)
//   o_asum [1179648,    1198080)   asum       (to sfdiv)
//   o_pad  [1198080,    1861632)   stok_pad   -> later sfa_pad (re-memset)
//   o_sf   [1861632,    2385920)   sf_raw/sf  -> later o_attn
//   o_qkv  [2385920,    3958784)   qkv        (to peadd)
// ---------------------------------------------------------------------------
extern "C" void kernel_launch(void* const* d_in, const int* in_sizes, int n_in,
                              void* d_out, int out_size, void* d_ws, size_t ws_size,
                              hipStream_t stream) {
    const float* x      = (const float*)d_in[0]; // (8,256,128,128) fp32
    const float* w_qkv  = (const float*)d_in[1]; // (768,256) fp32
    const float* w_pe   = (const float*)d_in[2]; // (256,1,3,3) fp32
    const float* w_proj = (const float*)d_in[3]; // (256,256) fp32
    float* out = (float*)d_out;

    float* ws = (float*)d_ws;
    const size_t o_aff  = 0;
    const size_t o_asum = 1179648;
    const size_t o_pad  = 1198080;
    const size_t o_sf   = 1861632;
    const size_t o_qkv  = 2385920;

    hipMemsetAsync(ws + o_pad, 0, 663552 * sizeof(float), stream);
    hipMemsetAsync(ws + o_sf,  0, 524288 * sizeof(float), stream);

    stoken_kernel<<<8 * 256 * 16, 128, 0, stream>>>(x, ws + o_pad);
    aff_agg_kernel<<<8 * 256, 256, 0, stream>>>(x, ws + o_pad, ws + o_aff,
                                                ws + o_asum, ws + o_sf);
    sfdiv_kernel<<<8 * 256, 256, 0, stream>>>(ws + o_sf, ws + o_asum, ws + o_sf);
    gemm_w<<<dim3(8, 12, 4), 256, 0, stream>>>(w_qkv, ws + o_sf, ws + o_qkv, 768, 0);
    // stok_pad dead; re-zero region for sfa_pad (borders must be 0)
    hipMemsetAsync(ws + o_pad, 0, 663552 * sizeof(float), stream);
    attn_kernel<<<dim3(8, 8, 4), 256, 0, stream>>>(ws + o_qkv, ws + o_sf);
    peadd_kernel<<<8 * 256, 256, 0, stream>>>(ws + o_qkv, w_pe, ws + o_sf);
    gemm_w<<<dim3(8, 4, 4), 256, 0, stream>>>(w_proj, ws + o_sf, ws + o_pad, 256, 1);
    scatter_kernel<<<8 * 256, 256, 0, stream>>>(ws + o_pad, ws + o_aff, out);
}

// Round 4
// 645.366 us; speedup vs baseline: 1.0805x; 1.0805x over previous
//
#include <hip/hip_runtime.h>
#include <cstdint>
#include <cstddef>

// ---------------------------------------------------------------------------
// StokenAttention forward, MI355X. B=8, C=256, H=W=128, stoken 8x8 -> 16x16
// grid, n=256 stokens/batch, 64 px/stoken, NH=8 heads, HD=KD=32.
// ALL inputs fp32, output fp32. R4: atomics -> coalesced agg (in d_out
// scratch) + fold gather; scatter rewritten for full-line stores.
// ---------------------------------------------------------------------------

#define AFF_SCALE 0.0625f               // 256^-0.5
#define ATTN_SCALE 0.17677669529663687f // 32^-0.5

// ---------------------------------------------------------------------------
// K1: stoken avg-pool. grid = B*C*16, block = 128. Zero-padded [b][c][18][18].
// ---------------------------------------------------------------------------
__global__ __launch_bounds__(128) void stoken_kernel(
    const float* __restrict__ x, float* __restrict__ stok_pad)
{
    int blk = blockIdx.x;
    int i  = blk & 15;
    int bc = blk >> 4;                 // b*256 + c
    int t  = threadIdx.x;              // col 0..127
    const float* xr = x + ((size_t)bc * 128 + i * 8) * 128 + t;
    float s = 0.f;
#pragma unroll
    for (int r = 0; r < 8; ++r) s += xr[r * 128];
    s += __shfl_down(s, 4, 64);
    s += __shfl_down(s, 2, 64);
    s += __shfl_down(s, 1, 64);
    if ((t & 7) == 0) {
        int j = t >> 3;  // 0..15
        stok_pad[((size_t)bc * 18 + (i + 1)) * 18 + (j + 1)] = s * (1.f / 64.f);
    }
}

// ---------------------------------------------------------------------------
// K2: fused affinity + asum + aggregation. grid = B*256, block = 256.
// Output agg[b][n][k][c] with coalesced stores (NO atomics; fold done in K3).
// ---------------------------------------------------------------------------
__global__ __launch_bounds__(256) void aff_agg_kernel(
    const float* __restrict__ x, const float* __restrict__ stok_pad,
    float* __restrict__ aff_g, float* __restrict__ asum_g,
    float* __restrict__ agg)
{
    __shared__ float pixs[256 * 65];          // [c][65 pad] fp32 (66.6 KB)
    __shared__ float part[4 * 64 * 9];        // wave partials
    __shared__ float affs[9 * 64];            // aff [k][p]

    int bn = blockIdx.x;
    int n = bn & 255, b = bn >> 8;
    int i = n >> 4, j = n & 15;
    int t = threadIdx.x;

    // ---- stage pixel tile: 256 c x 64 p ----
    {
        int c0 = t >> 3, pi = t & 7;
#pragma unroll
        for (int it = 0; it < 8; ++it) {
            int c = c0 + 32 * it;
            const float* xp = x + (((size_t)b * 256 + c) * 128 + i * 8 + pi) * 128 + j * 8;
            const float4 f0 = *(const float4*)&xp[0];
            const float4 f1 = *(const float4*)&xp[4];
            float* d = &pixs[c * 65 + pi * 8];
            d[0] = f0.x; d[1] = f0.y; d[2] = f0.z; d[3] = f0.w;
            d[4] = f1.x; d[5] = f1.y; d[6] = f1.z; d[7] = f1.w;
        }
    }
    __syncthreads();

    // ---- phase 1: partial logits (wave s = channel quarter) ----
    int s = t >> 6, p = t & 63;
    float acc[9] = {0.f,0.f,0.f,0.f,0.f,0.f,0.f,0.f,0.f};
    {
        const float* sp = stok_pad + ((size_t)b * 256 + s * 64) * 324 + i * 18 + j;
        for (int cc = 0; cc < 64; ++cc) {
            float px = pixs[(s * 64 + cc) * 65 + p];
            const float* q = sp + cc * 324;  // wave-uniform -> broadcast loads
            acc[0] += px * q[0];  acc[1] += px * q[1];  acc[2] += px * q[2];
            acc[3] += px * q[18]; acc[4] += px * q[19]; acc[5] += px * q[20];
            acc[6] += px * q[36]; acc[7] += px * q[37]; acc[8] += px * q[38];
        }
    }
#pragma unroll
    for (int k = 0; k < 9; ++k) part[(s * 64 + p) * 9 + k] = acc[k];
    __syncthreads();

    // ---- phase 1.5: softmax over 9 (wave 0), aff + asum writes ----
    if (t < 64) {
        float a[9];
        float mx = -1e30f;
#pragma unroll
        for (int k = 0; k < 9; ++k) {
            float v = (part[(0 * 64 + t) * 9 + k] + part[(1 * 64 + t) * 9 + k] +
                       part[(2 * 64 + t) * 9 + k] + part[(3 * 64 + t) * 9 + k]) * AFF_SCALE;
            a[k] = v;
            mx = fmaxf(mx, v);
        }
        float ssum = 0.f;
#pragma unroll
        for (int k = 0; k < 9; ++k) { a[k] = __expf(a[k] - mx); ssum += a[k]; }
        float inv = 1.f / ssum;
#pragma unroll
        for (int k = 0; k < 9; ++k) {
            a[k] *= inv;
            affs[k * 64 + t] = a[k];
            aff_g[(size_t)bn * 576 + k * 64 + t] = a[k];
        }
#pragma unroll
        for (int k = 0; k < 9; ++k) {
            float r = a[k];
            r += __shfl_down(r, 32, 64); r += __shfl_down(r, 16, 64);
            r += __shfl_down(r, 8, 64);  r += __shfl_down(r, 4, 64);
            r += __shfl_down(r, 2, 64);  r += __shfl_down(r, 1, 64);
            if (t == 0) asum_g[(size_t)bn * 9 + k] = r;
        }
    }
    __syncthreads();

    // ---- phase 2: aggregation, coalesced store (thread = channel) ----
    {
        int c = t;
        float a9[9] = {0.f,0.f,0.f,0.f,0.f,0.f,0.f,0.f,0.f};
        for (int p4 = 0; p4 < 16; ++p4) {
            float px0 = pixs[c * 65 + p4 * 4 + 0];
            float px1 = pixs[c * 65 + p4 * 4 + 1];
            float px2 = pixs[c * 65 + p4 * 4 + 2];
            float px3 = pixs[c * 65 + p4 * 4 + 3];
#pragma unroll
            for (int k = 0; k < 9; ++k) {
                const float4 av = *(const float4*)&affs[k * 64 + p4 * 4]; // uniform
                a9[k] += px0 * av.x + px1 * av.y + px2 * av.z + px3 * av.w;
            }
        }
#pragma unroll
        for (int k = 0; k < 9; ++k)
            agg[((size_t)bn * 9 + k) * 256 + c] = a9[k];
    }
}

// ---------------------------------------------------------------------------
// K3: fold(agg)/(fold(asum)+1e-12) -> sf[b][c][n]. grid = B*16 (b,y), blk 256.
// agg reads coalesced per (dy,dx) slice; sf writes coalesced via LDS transpose.
// ---------------------------------------------------------------------------
__global__ __launch_bounds__(256) void fold_div_kernel(
    const float* __restrict__ agg, const float* __restrict__ asum_g,
    float* __restrict__ sf)
{
    __shared__ float v[256 * 17];
    int b = blockIdx.x >> 4, y = blockIdx.x & 15;
    int t = threadIdx.x;  // c
    for (int x = 0; x < 16; ++x) {
        float af = 0.f, val = 0.f;
#pragma unroll
        for (int dy = 0; dy < 3; ++dy)
#pragma unroll
            for (int dx = 0; dx < 3; ++dx) {
                int ii = y + 1 - dy, jj = x + 1 - dx;
                if ((unsigned)ii < 16u && (unsigned)jj < 16u) {
                    int idx = (b * 256 + ii * 16 + jj) * 9 + dy * 3 + dx;
                    af  += asum_g[idx];                 // wave-uniform broadcast
                    val += agg[(size_t)idx * 256 + t];  // coalesced
                }
            }
        v[t * 17 + x] = val / (af + 1e-12f);
    }
    __syncthreads();
    int xw = t & 15, cw0 = t >> 4;
#pragma unroll
    for (int it = 0; it < 16; ++it) {
        int c = cw0 + it * 16;
        sf[((size_t)b * 256 + c) * 256 + y * 16 + xw] = v[c * 17 + xw];
    }
}

// ---------------------------------------------------------------------------
// K4/K7: GEMM out[b][o][n] = sum_c A[o][c] * Bm[b][c][n]. mode 0: [b][M][256].
// mode 1: write into padded [b][18][18][256] (+1 spatial offset).
// ---------------------------------------------------------------------------
__global__ __launch_bounds__(256) void gemm_w(
    const float* __restrict__ A, const float* __restrict__ Bm,
    float* __restrict__ Cout, int M, int mode)
{
    __shared__ float As[32 * 68];
    __shared__ float Bs[32 * 64];
    int b = blockIdx.x, o0 = blockIdx.y * 64, n0 = blockIdx.z * 64;
    int t = threadIdx.x;
    int tr = t >> 4, tc = t & 15;
    const float* Bb = Bm + (size_t)b * 256 * 256;
    float acc[4][4];
#pragma unroll
    for (int ii = 0; ii < 4; ++ii)
#pragma unroll
        for (int jj = 0; jj < 4; ++jj) acc[ii][jj] = 0.f;

    for (int k0 = 0; k0 < 256; k0 += 32) {
        {
            int ol = t >> 2, kq = (t & 3) * 8;
            const float* Ap = A + (size_t)(o0 + ol) * 256 + k0 + kq;
            const float4 f0 = *(const float4*)&Ap[0];
            const float4 f1 = *(const float4*)&Ap[4];
            As[(kq + 0) * 68 + ol] = f0.x; As[(kq + 1) * 68 + ol] = f0.y;
            As[(kq + 2) * 68 + ol] = f0.z; As[(kq + 3) * 68 + ol] = f0.w;
            As[(kq + 4) * 68 + ol] = f1.x; As[(kq + 5) * 68 + ol] = f1.y;
            As[(kq + 6) * 68 + ol] = f1.z; As[(kq + 7) * 68 + ol] = f1.w;
        }
#pragma unroll
        for (int i2 = 0; i2 < 8; ++i2) {
            int e = t + i2 * 256;
            int kl = e >> 6, nl = e & 63;
            Bs[kl * 64 + nl] = Bb[(size_t)(k0 + kl) * 256 + n0 + nl];
        }
        __syncthreads();
#pragma unroll
        for (int kk = 0; kk < 32; ++kk) {
            const float4 av = *(const float4*)&As[kk * 68 + tr * 4];
            const float4 bv = *(const float4*)&Bs[kk * 64 + tc * 4];
            acc[0][0] += av.x * bv.x; acc[0][1] += av.x * bv.y; acc[0][2] += av.x * bv.z; acc[0][3] += av.x * bv.w;
            acc[1][0] += av.y * bv.x; acc[1][1] += av.y * bv.y; acc[1][2] += av.y * bv.z; acc[1][3] += av.y * bv.w;
            acc[2][0] += av.z * bv.x; acc[2][1] += av.z * bv.y; acc[2][2] += av.z * bv.z; acc[2][3] += av.z * bv.w;
            acc[3][0] += av.w * bv.x; acc[3][1] += av.w * bv.y; acc[3][2] += av.w * bv.z; acc[3][3] += av.w * bv.w;
        }
        __syncthreads();
    }

    if (mode == 0) {
#pragma unroll
        for (int ii = 0; ii < 4; ++ii) {
            int o = o0 + tr * 4 + ii;
            float4 st = make_float4(acc[ii][0], acc[ii][1], acc[ii][2], acc[ii][3]);
            *(float4*)&Cout[((size_t)b * M + o) * 256 + n0 + tc * 4] = st;
        }
    } else {
#pragma unroll
        for (int jj = 0; jj < 4; ++jj) {
            int n = n0 + tc * 4 + jj;
            int y = n >> 4, x = n & 15;
            float4 st = make_float4(acc[0][jj], acc[1][jj], acc[2][jj], acc[3][jj]);
            *(float4*)&Cout[(((size_t)b * 18 + 1 + y) * 18 + 1 + x) * 256 + o0 + tr * 4] = st;
        }
    }
}

// ---------------------------------------------------------------------------
// K5: attention. grid = (8 b, 8 h, 4 n-tiles), block = 256.
// ---------------------------------------------------------------------------
__global__ __launch_bounds__(256) void attn_kernel(
    const float* __restrict__ qkv, float* __restrict__ o_attn)
{
    __shared__ float smem[9216];
    int b = blockIdx.x, h = blockIdx.y, nt = blockIdx.z;
    int t = threadIdx.x, nl = t & 63, mq = t >> 6;
    int n = nt * 64 + nl;

    {
        int dd = t >> 3, mb = (t & 7) * 32;
        const float* krow = qkv + ((size_t)b * 768 + h * 96 + 32 + dd) * 256;
#pragma unroll
        for (int e4 = 0; e4 < 8; ++e4) {
            int m = mb + e4 * 4;
            const float4 kw = *(const float4*)&krow[m];
            smem[(m + 0) * 32 + dd] = kw.x; smem[(m + 1) * 32 + dd] = kw.y;
            smem[(m + 2) * 32 + dd] = kw.z; smem[(m + 3) * 32 + dd] = kw.w;
        }
    }
    float q[32];
    {
        const float* qbase = qkv + ((size_t)b * 768 + h * 96) * 256 + n;
#pragma unroll
        for (int d = 0; d < 32; ++d) q[d] = qbase[(size_t)d * 256];
    }
    __syncthreads();

    float l[64];
#pragma unroll
    for (int e = 0; e < 64; ++e) {
        const float* kp = &smem[(mq * 64 + e) * 32];
        float s = 0.f;
#pragma unroll
        for (int d4 = 0; d4 < 8; ++d4) {
            const float4 kv4 = *(const float4*)&kp[d4 * 4];
            s += q[d4 * 4 + 0] * kv4.x + q[d4 * 4 + 1] * kv4.y +
                 q[d4 * 4 + 2] * kv4.z + q[d4 * 4 + 3] * kv4.w;
        }
        l[e] = s * ATTN_SCALE;
    }
    float mx = -1e30f;
#pragma unroll
    for (int e = 0; e < 64; ++e) mx = fmaxf(mx, l[e]);
    float sm = 0.f;
#pragma unroll
    for (int e = 0; e < 64; ++e) { l[e] = __expf(l[e] - mx); sm += l[e]; }
    __syncthreads();

    {
        int dd = t >> 3, mb = (t & 7) * 32;
        const float* vrow = qkv + ((size_t)b * 768 + h * 96 + 64 + dd) * 256;
#pragma unroll
        for (int e4 = 0; e4 < 8; ++e4) {
            int m = mb + e4 * 4;
            const float4 vw = *(const float4*)&vrow[m];
            smem[(m + 0) * 32 + dd] = vw.x; smem[(m + 1) * 32 + dd] = vw.y;
            smem[(m + 2) * 32 + dd] = vw.z; smem[(m + 3) * 32 + dd] = vw.w;
        }
    }
    __syncthreads();

    float oa[32];
#pragma unroll
    for (int d = 0; d < 32; ++d) oa[d] = 0.f;
#pragma unroll
    for (int e = 0; e < 64; ++e) {
        float pm = l[e];
        const float* vp = &smem[(mq * 64 + e) * 32];
#pragma unroll
        for (int d4 = 0; d4 < 8; ++d4) {
            const float4 vv = *(const float4*)&vp[d4 * 4];
            oa[d4 * 4 + 0] += pm * vv.x; oa[d4 * 4 + 1] += pm * vv.y;
            oa[d4 * 4 + 2] += pm * vv.z; oa[d4 * 4 + 3] += pm * vv.w;
        }
    }
    __syncthreads();

    float* op   = smem;          // [mq*64+nl][33]
    float* mxsm = smem + 8448;   // [idx][2]
    {
        int idx = mq * 64 + nl;
#pragma unroll
        for (int d = 0; d < 32; ++d) op[idx * 33 + d] = oa[d];
        mxsm[idx * 2 + 0] = mx;
        mxsm[idx * 2 + 1] = sm;
    }
    __syncthreads();

    if (t < 64) {
        float M2 = -1e30f;
#pragma unroll
        for (int q4 = 0; q4 < 4; ++q4) M2 = fmaxf(M2, mxsm[(q4 * 64 + t) * 2]);
        float w[4], S = 0.f;
#pragma unroll
        for (int q4 = 0; q4 < 4; ++q4) {
            w[q4] = __expf(mxsm[(q4 * 64 + t) * 2] - M2);
            S += mxsm[(q4 * 64 + t) * 2 + 1] * w[q4];
        }
        float inv = 1.f / S;
#pragma unroll
        for (int d = 0; d < 32; ++d) {
            float o = 0.f;
#pragma unroll
            for (int q4 = 0; q4 < 4; ++q4) o += op[(q4 * 64 + t) * 33 + d] * w[q4];
            o_attn[((size_t)b * 256 + h * 32 + d) * 256 + nt * 64 + t] = o * inv;
        }
    }
}

// ---------------------------------------------------------------------------
// K6: o += depthwise 3x3 PE conv of V. grid B*C, blk 256.
// ---------------------------------------------------------------------------
__global__ __launch_bounds__(256) void peadd_kernel(
    const float* __restrict__ qkv, const float* __restrict__ w_pe,
    float* __restrict__ o_attn)
{
    int bc = blockIdx.x;
    int b = bc >> 8, c = bc & 255;
    int t = threadIdx.x;
    int y = t >> 4, x = t & 15;
    int h = c >> 5, d = c & 31;
    const float* v = qkv + ((size_t)b * 768 + h * 96 + 64 + d) * 256;
    float acc = o_attn[(size_t)bc * 256 + t];
#pragma unroll
    for (int ky = 0; ky < 3; ++ky)
#pragma unroll
        for (int kx = 0; kx < 3; ++kx) {
            int yy = y + ky - 1, xx = x + kx - 1;
            if ((unsigned)yy < 16u && (unsigned)xx < 16u)
                acc += w_pe[c * 9 + ky * 3 + kx] * v[yy * 16 + xx];
        }
    o_attn[(size_t)bc * 256 + t] = acc;
}

// ---------------------------------------------------------------------------
// K8: scatter v2. grid = B*16i*8jp = 1024 blocks (2 adjacent stokens/block),
// block = 256. Stores are 4 full 64B lines per wave-instruction.
// out[b,c2,i*8+pi,j*8+pj] = sum_k sfa[b, c=(c2&3)*64+pi*8+pj, nbr k]
//                                  * aff[b, n, c2>>2, k]
// ---------------------------------------------------------------------------
__global__ __launch_bounds__(256) void scatter_kernel(
    const float* __restrict__ sfa_pad, const float* __restrict__ aff_g,
    float* __restrict__ out)
{
    __shared__ float s12[256 * 13]; // [cc][12 of 3x4 window]
    __shared__ float af[128 * 12];  // [jh*64+p][9]

    int blk = blockIdx.x;
    int jp = blk & 7, i = (blk >> 3) & 15, b = blk >> 7;
    int j0 = jp * 2;
    int t = threadIdx.x;

    // stage 3x4 neighborhood (covers both stokens' 3x3 windows), coalesced in c
#pragma unroll
    for (int s_i = 0; s_i < 12; ++s_i)
        s12[t * 13 + s_i] =
            sfa_pad[(((size_t)b * 18 + i + (s_i >> 2)) * 18 + j0 + (s_i & 3)) * 256 + t];
    // stage aff for both stokens
    for (int e = t; e < 1152; e += 256) {
        int jh = e / 576, rem = e % 576;
        int k = rem >> 6, p = rem & 63;
        af[(jh * 64 + p) * 12 + k] =
            aff_g[((size_t)(b * 256 + i * 16 + j0 + jh)) * 576 + k * 64 + p];
    }
    __syncthreads();

    int pj16 = t & 15, pi = (t >> 4) & 7, ch = t >> 7;
    int jh = pj16 >> 3, pjl = pj16 & 7;
    int ppix = pi * 8 + pjl;

    float sr[4][9];
#pragma unroll
    for (int q4 = 0; q4 < 4; ++q4) {
        int cc = q4 * 64 + ppix;
#pragma unroll
        for (int k = 0; k < 9; ++k)
            sr[q4][k] = s12[cc * 13 + (k / 3) * 4 + (k % 3) + jh];
    }

    size_t obase = (size_t)b * 256 * 16384 + (size_t)(i * 8 + pi) * 128 + j0 * 8 + pj16;
    const float* afp = &af[jh * 64 * 12];
    for (int c2 = ch * 128; c2 < ch * 128 + 128; ++c2) {
        const float* a = &afp[(c2 >> 2) * 12];
        const float* s = sr[c2 & 3];
        float v = s[0]*a[0] + s[1]*a[1] + s[2]*a[2] + s[3]*a[3] + s[4]*a[4]
                + s[5]*a[5] + s[6]*a[6] + s[7]*a[7] + s[8]*a[8];
        out[obase + (size_t)c2 * 16384] = v;
    }
}

// ---------------------------------------------------------------------------
// launch. Workspace (floats), 15.8 MB; agg (18.9 MB) lives in d_out scratch
// (dead before scatter writes out).
//   o_aff  [0,       1179648)  aff       (live to end)
//   o_asum [1179648, 1198080)  asum      (to fold_div)
//   o_pad  [1198080, 1861632)  stok_pad  -> later sfa_pad (re-memset)
//   o_sf   [1861632, 2385920)  sf        -> later o_attn
//   o_qkv  [2385920, 3958784)  qkv       (to peadd)
// ---------------------------------------------------------------------------
extern "C" void kernel_launch(void* const* d_in, const int* in_sizes, int n_in,
                              void* d_out, int out_size, void* d_ws, size_t ws_size,
                              hipStream_t stream) {
    const float* x      = (const float*)d_in[0];
    const float* w_qkv  = (const float*)d_in[1];
    const float* w_pe   = (const float*)d_in[2];
    const float* w_proj = (const float*)d_in[3];
    float* out = (float*)d_out;
    float* agg = (float*)d_out;  // scratch: 18.9 MB << 134 MB, dead before scatter

    float* ws = (float*)d_ws;
    const size_t o_aff  = 0;
    const size_t o_asum = 1179648;
    const size_t o_pad  = 1198080;
    const size_t o_sf   = 1861632;
    const size_t o_qkv  = 2385920;

    hipMemsetAsync(ws + o_pad, 0, 663552 * sizeof(float), stream);

    stoken_kernel<<<8 * 256 * 16, 128, 0, stream>>>(x, ws + o_pad);
    aff_agg_kernel<<<8 * 256, 256, 0, stream>>>(x, ws + o_pad, ws + o_aff,
                                                ws + o_asum, agg);
    fold_div_kernel<<<8 * 16, 256, 0, stream>>>(agg, ws + o_asum, ws + o_sf);
    gemm_w<<<dim3(8, 12, 4), 256, 0, stream>>>(w_qkv, ws + o_sf, ws + o_qkv, 768, 0);
    // stok_pad dead; re-zero region for sfa_pad (borders must be 0)
    hipMemsetAsync(ws + o_pad, 0, 663552 * sizeof(float), stream);
    attn_kernel<<<dim3(8, 8, 4), 256, 0, stream>>>(ws + o_qkv, ws + o_sf);
    peadd_kernel<<<8 * 256, 256, 0, stream>>>(ws + o_qkv, w_pe, ws + o_sf);
    gemm_w<<<dim3(8, 4, 4), 256, 0, stream>>>(w_proj, ws + o_sf, ws + o_pad, 256, 1);
    scatter_kernel<<<8 * 16 * 8, 256, 0, stream>>>(ws + o_pad, ws + o_aff, out);
}

// Round 6
// 493.904 us; speedup vs baseline: 1.4119x; 1.3067x over previous
//
#include <hip/hip_runtime.h>
#include <cstdint>
#include <cstddef>

// ---------------------------------------------------------------------------
// StokenAttention forward, MI355X. B=8, C=256, H=W=128, stoken 8x8 -> 16x16
// grid, n=256 stokens/batch, 64 px/stoken, NH=8 heads, HD=KD=32.
// ALL inputs fp32, output fp32. R6: fix scatter v3 aff_s stride 146 -> 577
// (per-j extent is 576 floats; 146 was a stale v2 remnant causing LDS
// overlap/OOB -> absmax 6.8e-2).
// ---------------------------------------------------------------------------

#define AFF_SCALE 0.0625f               // 256^-0.5
#define ATTN_SCALE 0.17677669529663687f // 32^-0.5

// ---------------------------------------------------------------------------
// K1: stoken avg-pool. grid = B*C*16, block = 128. Zero-padded [b][c][18][18].
// ---------------------------------------------------------------------------
__global__ __launch_bounds__(128) void stoken_kernel(
    const float* __restrict__ x, float* __restrict__ stok_pad)
{
    int blk = blockIdx.x;
    int i  = blk & 15;
    int bc = blk >> 4;                 // b*256 + c
    int t  = threadIdx.x;              // col 0..127
    const float* xr = x + ((size_t)bc * 128 + i * 8) * 128 + t;
    float s = 0.f;
#pragma unroll
    for (int r = 0; r < 8; ++r) s += xr[r * 128];
    s += __shfl_down(s, 4, 64);
    s += __shfl_down(s, 2, 64);
    s += __shfl_down(s, 1, 64);
    if ((t & 7) == 0) {
        int j = t >> 3;  // 0..15
        stok_pad[((size_t)bc * 18 + (i + 1)) * 18 + (j + 1)] = s * (1.f / 64.f);
    }
}

// ---------------------------------------------------------------------------
// K2: fused affinity + asum + aggregation. grid = B*256, block = 256.
// Output agg[b][n][k][c] with coalesced stores (NO atomics; fold done in K3).
// ---------------------------------------------------------------------------
__global__ __launch_bounds__(256) void aff_agg_kernel(
    const float* __restrict__ x, const float* __restrict__ stok_pad,
    float* __restrict__ aff_g, float* __restrict__ asum_g,
    float* __restrict__ agg)
{
    __shared__ float pixs[256 * 65];          // [c][65 pad] fp32 (66.6 KB)
    __shared__ float part[4 * 64 * 9];        // wave partials
    __shared__ float affs[9 * 64];            // aff [k][p]

    int bn = blockIdx.x;
    int n = bn & 255, b = bn >> 8;
    int i = n >> 4, j = n & 15;
    int t = threadIdx.x;

    // ---- stage pixel tile: 256 c x 64 p ----
    {
        int c0 = t >> 3, pi = t & 7;
#pragma unroll
        for (int it = 0; it < 8; ++it) {
            int c = c0 + 32 * it;
            const float* xp = x + (((size_t)b * 256 + c) * 128 + i * 8 + pi) * 128 + j * 8;
            const float4 f0 = *(const float4*)&xp[0];
            const float4 f1 = *(const float4*)&xp[4];
            float* d = &pixs[c * 65 + pi * 8];
            d[0] = f0.x; d[1] = f0.y; d[2] = f0.z; d[3] = f0.w;
            d[4] = f1.x; d[5] = f1.y; d[6] = f1.z; d[7] = f1.w;
        }
    }
    __syncthreads();

    // ---- phase 1: partial logits (wave s = channel quarter) ----
    int s = t >> 6, p = t & 63;
    float acc[9] = {0.f,0.f,0.f,0.f,0.f,0.f,0.f,0.f,0.f};
    {
        const float* sp = stok_pad + ((size_t)b * 256 + s * 64) * 324 + i * 18 + j;
        for (int cc = 0; cc < 64; ++cc) {
            float px = pixs[(s * 64 + cc) * 65 + p];
            const float* q = sp + cc * 324;  // wave-uniform -> broadcast loads
            acc[0] += px * q[0];  acc[1] += px * q[1];  acc[2] += px * q[2];
            acc[3] += px * q[18]; acc[4] += px * q[19]; acc[5] += px * q[20];
            acc[6] += px * q[36]; acc[7] += px * q[37]; acc[8] += px * q[38];
        }
    }
#pragma unroll
    for (int k = 0; k < 9; ++k) part[(s * 64 + p) * 9 + k] = acc[k];
    __syncthreads();

    // ---- phase 1.5: softmax over 9 (wave 0), aff + asum writes ----
    if (t < 64) {
        float a[9];
        float mx = -1e30f;
#pragma unroll
        for (int k = 0; k < 9; ++k) {
            float v = (part[(0 * 64 + t) * 9 + k] + part[(1 * 64 + t) * 9 + k] +
                       part[(2 * 64 + t) * 9 + k] + part[(3 * 64 + t) * 9 + k]) * AFF_SCALE;
            a[k] = v;
            mx = fmaxf(mx, v);
        }
        float ssum = 0.f;
#pragma unroll
        for (int k = 0; k < 9; ++k) { a[k] = __expf(a[k] - mx); ssum += a[k]; }
        float inv = 1.f / ssum;
#pragma unroll
        for (int k = 0; k < 9; ++k) {
            a[k] *= inv;
            affs[k * 64 + t] = a[k];
            aff_g[(size_t)bn * 576 + k * 64 + t] = a[k];
        }
#pragma unroll
        for (int k = 0; k < 9; ++k) {
            float r = a[k];
            r += __shfl_down(r, 32, 64); r += __shfl_down(r, 16, 64);
            r += __shfl_down(r, 8, 64);  r += __shfl_down(r, 4, 64);
            r += __shfl_down(r, 2, 64);  r += __shfl_down(r, 1, 64);
            if (t == 0) asum_g[(size_t)bn * 9 + k] = r;
        }
    }
    __syncthreads();

    // ---- phase 2: aggregation, coalesced store (thread = channel) ----
    {
        int c = t;
        float a9[9] = {0.f,0.f,0.f,0.f,0.f,0.f,0.f,0.f,0.f};
        for (int p4 = 0; p4 < 16; ++p4) {
            float px0 = pixs[c * 65 + p4 * 4 + 0];
            float px1 = pixs[c * 65 + p4 * 4 + 1];
            float px2 = pixs[c * 65 + p4 * 4 + 2];
            float px3 = pixs[c * 65 + p4 * 4 + 3];
#pragma unroll
            for (int k = 0; k < 9; ++k) {
                const float4 av = *(const float4*)&affs[k * 64 + p4 * 4]; // uniform
                a9[k] += px0 * av.x + px1 * av.y + px2 * av.z + px3 * av.w;
            }
        }
#pragma unroll
        for (int k = 0; k < 9; ++k)
            agg[((size_t)bn * 9 + k) * 256 + c] = a9[k];
    }
}

// ---------------------------------------------------------------------------
// K3: fold(agg)/(fold(asum)+1e-12) -> sf[b][c][n]. grid = B*16 (b,y), blk 256.
// ---------------------------------------------------------------------------
__global__ __launch_bounds__(256) void fold_div_kernel(
    const float* __restrict__ agg, const float* __restrict__ asum_g,
    float* __restrict__ sf)
{
    __shared__ float v[256 * 17];
    int b = blockIdx.x >> 4, y = blockIdx.x & 15;
    int t = threadIdx.x;  // c
    for (int x = 0; x < 16; ++x) {
        float af = 0.f, val = 0.f;
#pragma unroll
        for (int dy = 0; dy < 3; ++dy)
#pragma unroll
            for (int dx = 0; dx < 3; ++dx) {
                int ii = y + 1 - dy, jj = x + 1 - dx;
                if ((unsigned)ii < 16u && (unsigned)jj < 16u) {
                    int idx = (b * 256 + ii * 16 + jj) * 9 + dy * 3 + dx;
                    af  += asum_g[idx];                 // wave-uniform broadcast
                    val += agg[(size_t)idx * 256 + t];  // coalesced
                }
            }
        v[t * 17 + x] = val / (af + 1e-12f);
    }
    __syncthreads();
    int xw = t & 15, cw0 = t >> 4;
#pragma unroll
    for (int it = 0; it < 16; ++it) {
        int c = cw0 + it * 16;
        sf[((size_t)b * 256 + c) * 256 + y * 16 + xw] = v[c * 17 + xw];
    }
}

// ---------------------------------------------------------------------------
// K4/K7: GEMM out[b][o][n] = sum_c A[o][c] * Bm[b][c][n]. mode 0: [b][M][256].
// mode 1: write into padded [b][18][18][256] (+1 spatial offset).
// ---------------------------------------------------------------------------
__global__ __launch_bounds__(256) void gemm_w(
    const float* __restrict__ A, const float* __restrict__ Bm,
    float* __restrict__ Cout, int M, int mode)
{
    __shared__ float As[32 * 68];
    __shared__ float Bs[32 * 64];
    int b = blockIdx.x, o0 = blockIdx.y * 64, n0 = blockIdx.z * 64;
    int t = threadIdx.x;
    int tr = t >> 4, tc = t & 15;
    const float* Bb = Bm + (size_t)b * 256 * 256;
    float acc[4][4];
#pragma unroll
    for (int ii = 0; ii < 4; ++ii)
#pragma unroll
        for (int jj = 0; jj < 4; ++jj) acc[ii][jj] = 0.f;

    for (int k0 = 0; k0 < 256; k0 += 32) {
        {
            int ol = t >> 2, kq = (t & 3) * 8;
            const float* Ap = A + (size_t)(o0 + ol) * 256 + k0 + kq;
            const float4 f0 = *(const float4*)&Ap[0];
            const float4 f1 = *(const float4*)&Ap[4];
            As[(kq + 0) * 68 + ol] = f0.x; As[(kq + 1) * 68 + ol] = f0.y;
            As[(kq + 2) * 68 + ol] = f0.z; As[(kq + 3) * 68 + ol] = f0.w;
            As[(kq + 4) * 68 + ol] = f1.x; As[(kq + 5) * 68 + ol] = f1.y;
            As[(kq + 6) * 68 + ol] = f1.z; As[(kq + 7) * 68 + ol] = f1.w;
        }
#pragma unroll
        for (int i2 = 0; i2 < 8; ++i2) {
            int e = t + i2 * 256;
            int kl = e >> 6, nl = e & 63;
            Bs[kl * 64 + nl] = Bb[(size_t)(k0 + kl) * 256 + n0 + nl];
        }
        __syncthreads();
#pragma unroll
        for (int kk = 0; kk < 32; ++kk) {
            const float4 av = *(const float4*)&As[kk * 68 + tr * 4];
            const float4 bv = *(const float4*)&Bs[kk * 64 + tc * 4];
            acc[0][0] += av.x * bv.x; acc[0][1] += av.x * bv.y; acc[0][2] += av.x * bv.z; acc[0][3] += av.x * bv.w;
            acc[1][0] += av.y * bv.x; acc[1][1] += av.y * bv.y; acc[1][2] += av.y * bv.z; acc[1][3] += av.y * bv.w;
            acc[2][0] += av.z * bv.x; acc[2][1] += av.z * bv.y; acc[2][2] += av.z * bv.z; acc[2][3] += av.z * bv.w;
            acc[3][0] += av.w * bv.x; acc[3][1] += av.w * bv.y; acc[3][2] += av.w * bv.z; acc[3][3] += av.w * bv.w;
        }
        __syncthreads();
    }

    if (mode == 0) {
#pragma unroll
        for (int ii = 0; ii < 4; ++ii) {
            int o = o0 + tr * 4 + ii;
            float4 st = make_float4(acc[ii][0], acc[ii][1], acc[ii][2], acc[ii][3]);
            *(float4*)&Cout[((size_t)b * M + o) * 256 + n0 + tc * 4] = st;
        }
    } else {
#pragma unroll
        for (int jj = 0; jj < 4; ++jj) {
            int n = n0 + tc * 4 + jj;
            int y = n >> 4, x = n & 15;
            float4 st = make_float4(acc[0][jj], acc[1][jj], acc[2][jj], acc[3][jj]);
            *(float4*)&Cout[(((size_t)b * 18 + 1 + y) * 18 + 1 + x) * 256 + o0 + tr * 4] = st;
        }
    }
}

// ---------------------------------------------------------------------------
// K5: attention. grid = (8 b, 8 h, 4 n-tiles), block = 256.
// ---------------------------------------------------------------------------
__global__ __launch_bounds__(256) void attn_kernel(
    const float* __restrict__ qkv, float* __restrict__ o_attn)
{
    __shared__ float smem[9216];
    int b = blockIdx.x, h = blockIdx.y, nt = blockIdx.z;
    int t = threadIdx.x, nl = t & 63, mq = t >> 6;
    int n = nt * 64 + nl;

    {
        int dd = t >> 3, mb = (t & 7) * 32;
        const float* krow = qkv + ((size_t)b * 768 + h * 96 + 32 + dd) * 256;
#pragma unroll
        for (int e4 = 0; e4 < 8; ++e4) {
            int m = mb + e4 * 4;
            const float4 kw = *(const float4*)&krow[m];
            smem[(m + 0) * 32 + dd] = kw.x; smem[(m + 1) * 32 + dd] = kw.y;
            smem[(m + 2) * 32 + dd] = kw.z; smem[(m + 3) * 32 + dd] = kw.w;
        }
    }
    float q[32];
    {
        const float* qbase = qkv + ((size_t)b * 768 + h * 96) * 256 + n;
#pragma unroll
        for (int d = 0; d < 32; ++d) q[d] = qbase[(size_t)d * 256];
    }
    __syncthreads();

    float l[64];
#pragma unroll
    for (int e = 0; e < 64; ++e) {
        const float* kp = &smem[(mq * 64 + e) * 32];
        float s = 0.f;
#pragma unroll
        for (int d4 = 0; d4 < 8; ++d4) {
            const float4 kv4 = *(const float4*)&kp[d4 * 4];
            s += q[d4 * 4 + 0] * kv4.x + q[d4 * 4 + 1] * kv4.y +
                 q[d4 * 4 + 2] * kv4.z + q[d4 * 4 + 3] * kv4.w;
        }
        l[e] = s * ATTN_SCALE;
    }
    float mx = -1e30f;
#pragma unroll
    for (int e = 0; e < 64; ++e) mx = fmaxf(mx, l[e]);
    float sm = 0.f;
#pragma unroll
    for (int e = 0; e < 64; ++e) { l[e] = __expf(l[e] - mx); sm += l[e]; }
    __syncthreads();

    {
        int dd = t >> 3, mb = (t & 7) * 32;
        const float* vrow = qkv + ((size_t)b * 768 + h * 96 + 64 + dd) * 256;
#pragma unroll
        for (int e4 = 0; e4 < 8; ++e4) {
            int m = mb + e4 * 4;
            const float4 vw = *(const float4*)&vrow[m];
            smem[(m + 0) * 32 + dd] = vw.x; smem[(m + 1) * 32 + dd] = vw.y;
            smem[(m + 2) * 32 + dd] = vw.z; smem[(m + 3) * 32 + dd] = vw.w;
        }
    }
    __syncthreads();

    float oa[32];
#pragma unroll
    for (int d = 0; d < 32; ++d) oa[d] = 0.f;
#pragma unroll
    for (int e = 0; e < 64; ++e) {
        float pm = l[e];
        const float* vp = &smem[(mq * 64 + e) * 32];
#pragma unroll
        for (int d4 = 0; d4 < 8; ++d4) {
            const float4 vv = *(const float4*)&vp[d4 * 4];
            oa[d4 * 4 + 0] += pm * vv.x; oa[d4 * 4 + 1] += pm * vv.y;
            oa[d4 * 4 + 2] += pm * vv.z; oa[d4 * 4 + 3] += pm * vv.w;
        }
    }
    __syncthreads();

    float* op   = smem;          // [mq*64+nl][33]
    float* mxsm = smem + 8448;   // [idx][2]
    {
        int idx = mq * 64 + nl;
#pragma unroll
        for (int d = 0; d < 32; ++d) op[idx * 33 + d] = oa[d];
        mxsm[idx * 2 + 0] = mx;
        mxsm[idx * 2 + 1] = sm;
    }
    __syncthreads();

    if (t < 64) {
        float M2 = -1e30f;
#pragma unroll
        for (int q4 = 0; q4 < 4; ++q4) M2 = fmaxf(M2, mxsm[(q4 * 64 + t) * 2]);
        float w[4], S = 0.f;
#pragma unroll
        for (int q4 = 0; q4 < 4; ++q4) {
            w[q4] = __expf(mxsm[(q4 * 64 + t) * 2] - M2);
            S += mxsm[(q4 * 64 + t) * 2 + 1] * w[q4];
        }
        float inv = 1.f / S;
#pragma unroll
        for (int d = 0; d < 32; ++d) {
            float o = 0.f;
#pragma unroll
            for (int q4 = 0; q4 < 4; ++q4) o += op[(q4 * 64 + t) * 33 + d] * w[q4];
            o_attn[((size_t)b * 256 + h * 32 + d) * 256 + nt * 64 + t] = o * inv;
        }
    }
}

// ---------------------------------------------------------------------------
// K6: o += depthwise 3x3 PE conv of V. grid B*C, blk 256.
// ---------------------------------------------------------------------------
__global__ __launch_bounds__(256) void peadd_kernel(
    const float* __restrict__ qkv, const float* __restrict__ w_pe,
    float* __restrict__ o_attn)
{
    int bc = blockIdx.x;
    int b = bc >> 8, c = bc & 255;
    int t = threadIdx.x;
    int y = t >> 4, x = t & 15;
    int h = c >> 5, d = c & 31;
    const float* v = qkv + ((size_t)b * 768 + h * 96 + 64 + d) * 256;
    float acc = o_attn[(size_t)bc * 256 + t];
#pragma unroll
    for (int ky = 0; ky < 3; ++ky)
#pragma unroll
        for (int kx = 0; kx < 3; ++kx) {
            int yy = y + ky - 1, xx = x + kx - 1;
            if ((unsigned)yy < 16u && (unsigned)xx < 16u)
                acc += w_pe[c * 9 + ky * 3 + kx] * v[yy * 16 + xx];
        }
    o_attn[(size_t)bc * 256 + t] = acc;
}

// ---------------------------------------------------------------------------
// K8: scatter v3 (fixed). grid = (b,i,pi) = 1024 blocks, block = 256.
// Block owns output row y = i*8+pi for ALL 256 c2 and all 128 x. Stores are
// 64-lane 256B contiguous (full 128B lines, no write-allocate).
// out[b,c2,y,x] = sum_k sfa_pad[b][i+dy][j+dx][(c2&3)*64+pi*8+pj]
//                       * aff[b, i*16+j][c2>>2][k],  j=x>>3, pj=x&7
// ---------------------------------------------------------------------------
__global__ __launch_bounds__(256) void scatter_kernel(
    const float* __restrict__ sfa_pad, const float* __restrict__ aff_g,
    float* __restrict__ out)
{
    __shared__ float ss[3 * 18 * 40];   // [dy][col][idx=q*8+d], stride 40
    __shared__ float aff_s[16 * 577];   // [j][p*9+k], stride 577 (>=576)

    int blk = blockIdx.x;
    int pi = blk & 7, i = (blk >> 3) & 15, b = blk >> 7;
    int t = threadIdx.x;

    // stage sfa neighborhood: 3 rows x 18 cols x 32 channels (this pi's slice)
    for (int e = t; e < 1728; e += 256) {
        int dy = e / 576, rem = e % 576;
        int col = rem >> 5, idx = rem & 31;
        int q = idx >> 3, d = idx & 7;
        ss[(dy * 18 + col) * 40 + idx] =
            sfa_pad[(((size_t)b * 18 + i + dy) * 18 + col) * 256 + q * 64 + pi * 8 + d];
    }
    // stage aff for the 16 stokens of row i: [j][p*9+k]
    {
        const float* ag = aff_g + ((size_t)b * 256 + i * 16) * 576;
        for (int e = t; e < 9216; e += 256) {
            int j = e / 576, rem = e % 576;
            int k = rem >> 6, p = rem & 63;
            aff_s[j * 577 + p * 9 + k] = ag[j * 576 + rem];
        }
    }
    __syncthreads();

    int lane = t & 63, w = t >> 6;
    int j0 = lane >> 3, pj = lane & 7;
    int j1 = j0 + 8;

    // register-cache the 2x36 sfa values this lane needs
    float S0[4][9], S1[4][9];
#pragma unroll
    for (int q = 0; q < 4; ++q)
#pragma unroll
        for (int k = 0; k < 9; ++k) {
            int dy = k / 3, dx = k % 3;
            S0[q][k] = ss[(dy * 18 + j0 + dx) * 40 + q * 8 + pj];
            S1[q][k] = ss[(dy * 18 + j1 + dx) * 40 + q * 8 + pj];
        }

    int y = i * 8 + pi;
    size_t ob = (size_t)b * 256 * 16384 + (size_t)y * 128;
    const float* A0 = &aff_s[j0 * 577];
    const float* A1 = &aff_s[j1 * 577];
    for (int p = w * 16; p < w * 16 + 16; ++p) {
        float a0[9], a1[9];
#pragma unroll
        for (int k = 0; k < 9; ++k) { a0[k] = A0[p * 9 + k]; a1[k] = A1[p * 9 + k]; }
#pragma unroll
        for (int q = 0; q < 4; ++q) {
            int c2 = p * 4 + q;
            float v0 = 0.f, v1 = 0.f;
#pragma unroll
            for (int k = 0; k < 9; ++k) {
                v0 += S0[q][k] * a0[k];
                v1 += S1[q][k] * a1[k];
            }
            out[ob + (size_t)c2 * 16384 + lane] = v0;
            out[ob + (size_t)c2 * 16384 + 64 + lane] = v1;
        }
    }
}

// ---------------------------------------------------------------------------
// launch. Workspace (floats), 15.8 MB; agg (18.9 MB) lives in d_out scratch
// (dead before scatter writes out).
// ---------------------------------------------------------------------------
extern "C" void kernel_launch(void* const* d_in, const int* in_sizes, int n_in,
                              void* d_out, int out_size, void* d_ws, size_t ws_size,
                              hipStream_t stream) {
    const float* x      = (const float*)d_in[0];
    const float* w_qkv  = (const float*)d_in[1];
    const float* w_pe   = (const float*)d_in[2];
    const float* w_proj = (const float*)d_in[3];
    float* out = (float*)d_out;
    float* agg = (float*)d_out;  // scratch: 18.9 MB << 134 MB, dead before scatter

    float* ws = (float*)d_ws;
    const size_t o_aff  = 0;
    const size_t o_asum = 1179648;
    const size_t o_pad  = 1198080;
    const size_t o_sf   = 1861632;
    const size_t o_qkv  = 2385920;

    hipMemsetAsync(ws + o_pad, 0, 663552 * sizeof(float), stream);

    stoken_kernel<<<8 * 256 * 16, 128, 0, stream>>>(x, ws + o_pad);
    aff_agg_kernel<<<8 * 256, 256, 0, stream>>>(x, ws + o_pad, ws + o_aff,
                                                ws + o_asum, agg);
    fold_div_kernel<<<8 * 16, 256, 0, stream>>>(agg, ws + o_asum, ws + o_sf);
    gemm_w<<<dim3(8, 12, 4), 256, 0, stream>>>(w_qkv, ws + o_sf, ws + o_qkv, 768, 0);
    // stok_pad dead; re-zero region for sfa_pad (borders must be 0)
    hipMemsetAsync(ws + o_pad, 0, 663552 * sizeof(float), stream);
    attn_kernel<<<dim3(8, 8, 4), 256, 0, stream>>>(ws + o_qkv, ws + o_sf);
    peadd_kernel<<<8 * 256, 256, 0, stream>>>(ws + o_qkv, w_pe, ws + o_sf);
    gemm_w<<<dim3(8, 4, 4), 256, 0, stream>>>(w_proj, ws + o_sf, ws + o_pad, 256, 1);
    scatter_kernel<<<8 * 16 * 8, 256, 0, stream>>>(ws + o_pad, ws + o_aff, out);
}